// Round 9
// baseline (127.023 us; speedup 1.0000x reference)
//
#include <hip/hip_runtime.h>

// Gemma3n AltUp fused, R9: token-per-wave, DE-CONVOYED memory flow.
// Every prior structure pinned at ~3.6 TB/s HBM (57% of the 6.3 TB/s copy
// rate) regardless of occupancy/burst/NT — consistent with chip-wide
// read-storm/write-storm convoying from the all-loads -> reduce -> all-stores
// phase shape. This version keeps the reduce phase minimal (x0+activated
// only, in-register, shfl-only reduce) and streams planes 1-3 in a
// fine-grained load/store interleaved loop with one-chunk prefetch, like the
// copy microbenchmark that reaches 6.3 TB/s.
// Shapes: hidden_states [4, T, H], activated [T, H], w_norm [H],
//         W_router [4, H], W_pred [16, 4], W_corr [4, 4], out [4, T, H]
// T = B*S = 8192, H = 2048, fp32. HBM ~427 MB after L3 absorption.

constexpr int H = 2048;
constexpr int NC = 8;          // chunks per wave: H / (64 lanes * 4 floats)
constexpr float EPS = 1e-6f;

typedef float f32x4 __attribute__((ext_vector_type(4)));

__global__ __launch_bounds__(256) void altup_deconvoy(
    const float* __restrict__ hs,       // [4, T, H]
    const float* __restrict__ act,      // [T, H]
    const float* __restrict__ w_norm,   // [H]
    const float* __restrict__ W_router, // [4, H]
    const float* __restrict__ W_pred,   // [16, 4]
    const float* __restrict__ W_corr,   // [4, 4]
    float* __restrict__ out,            // [4, T, H]
    long long T)
{
    const int lane = threadIdx.x & 63;
    const int wv   = threadIdx.x >> 6;
    const long long t = (long long)blockIdx.x * 4 + wv;
    if (t >= T) return;
    const long long row = t * (long long)H;
    const long long plane = T * (long long)H;
    const int base = lane * 4;

    const float* p0 = hs + row;              // plane 0 row
    const float* p1 = hs + plane + row;
    const float* p2 = hs + 2 * plane + row;
    const float* p3 = hs + 3 * plane + row;
    const float* pc = act + row;
    float* o0 = out + row;
    float* o1 = out + plane + row;
    float* o2 = out + 2 * plane + row;
    float* o3 = out + 3 * plane + row;

    // ---- phase 1: stage x0 + activated in registers, accumulate partials ----
    f32x4 x0[NC], xc[NC];
    float p[10];
#pragma unroll
    for (int i = 0; i < 10; ++i) p[i] = 0.f;

#pragma unroll
    for (int c = 0; c < NC; ++c) {
        const int off = c * 256 + base;
        x0[c] = *reinterpret_cast<const f32x4*>(p0 + off);
        xc[c] = *reinterpret_cast<const f32x4*>(pc + off);
    }
#pragma unroll
    for (int c = 0; c < NC; ++c) {
        const int off = c * 256 + base;
        const f32x4 wn = *reinterpret_cast<const f32x4*>(w_norm + off);
#pragma unroll
        for (int e = 0; e < 4; ++e) {
            p[0] += x0[c][e] * x0[c][e];
            p[5] += xc[c][e] * xc[c][e];
        }
#pragma unroll
        for (int i = 0; i < 4; ++i) {
            const f32x4 wr = *reinterpret_cast<const f32x4*>(W_router + i * H + off);
            float da = 0.f, dc = 0.f;
#pragma unroll
            for (int e = 0; e < 4; ++e) {
                const float wre = wn[e] * wr[e];
                da += x0[c][e] * wre;
                dc += xc[c][e] * wre;
            }
            p[1 + i] += da; p[6 + i] += dc;
        }
    }

    // ---- in-wave butterfly reduce (no LDS, no barrier) ----
#pragma unroll
    for (int m = 1; m < 64; m <<= 1) {
#pragma unroll
        for (int i = 0; i < 10; ++i) p[i] += __shfl_xor(p[i], m, 64);
    }

    // ---- coefficient math (per-lane redundant; weights scalar-broadcast) ----
    const float ris = 1.0f / (float)H;
    const float inv_a = rsqrtf(p[0] * ris + EPS) * ris;
    const float inv_c = rsqrtf(p[5] * ris + EPS) * ris;
    float mods[4], modsc[4];
#pragma unroll
    for (int i = 0; i < 4; ++i) {
        mods[i]  = tanhf(p[1 + i] * inv_a);
        modsc[i] = tanhf(p[6 + i] * inv_c);
    }
    // coefs = mods @ W_pred.T -> reshape [4][4] -> swapaxes:
    // coefT[k][j] = sum_m mods[m] * W_pred[(j*4+k)*4 + m]
    float coefT[4][4];
#pragma unroll
    for (int j = 0; j < 4; ++j)
#pragma unroll
        for (int k = 0; k < 4; ++k) {
            float s = 0.f;
#pragma unroll
            for (int m = 0; m < 4; ++m) s += mods[m] * W_pred[(j * 4 + k) * 4 + m];
            coefT[k][j] = s;
        }
    float ccoef[4];
#pragma unroll
    for (int j = 0; j < 4; ++j) {
        float s = 1.0f;
#pragma unroll
        for (int m = 0; m < 4; ++m) s += modsc[m] * W_corr[j * 4 + m];
        ccoef[j] = s;
    }

    // ---- phase 2: fine-grained mixed stream with one-chunk prefetch ----
    // per iteration: 3 loads (next chunk) + compute + 4 stores (current chunk)
    f32x4 c1 = *reinterpret_cast<const f32x4*>(p1 + base);
    f32x4 c2 = *reinterpret_cast<const f32x4*>(p2 + base);
    f32x4 c3 = *reinterpret_cast<const f32x4*>(p3 + base);

#pragma unroll
    for (int c = 0; c < NC; ++c) {
        const int off = c * 256 + base;
        f32x4 n1, n2, n3;
        if (c + 1 < NC) {
            const int noff = off + 256;
            n1 = *reinterpret_cast<const f32x4*>(p1 + noff);
            n2 = *reinterpret_cast<const f32x4*>(p2 + noff);
            n3 = *reinterpret_cast<const f32x4*>(p3 + noff);
        }

        f32x4 r0, r1, r2, r3;
#pragma unroll
        for (int e = 0; e < 4; ++e) {
            const float xk[4] = { x0[c][e], c1[e], c2[e], c3[e] };
            float pred[4];
#pragma unroll
            for (int j = 0; j < 4; ++j) {
                float s = xk[j]; // residual
#pragma unroll
                for (int k = 0; k < 4; ++k) s += xk[k] * coefT[k][j];
                pred[j] = s;
            }
            const float innov = xc[c][e] - pred[0];
            r0[e] = pred[0] + innov * ccoef[0];
            r1[e] = pred[1] + innov * ccoef[1];
            r2[e] = pred[2] + innov * ccoef[2];
            r3[e] = pred[3] + innov * ccoef[3];
        }
        *reinterpret_cast<f32x4*>(o0 + off) = r0;
        *reinterpret_cast<f32x4*>(o1 + off) = r1;
        *reinterpret_cast<f32x4*>(o2 + off) = r2;
        *reinterpret_cast<f32x4*>(o3 + off) = r3;

        c1 = n1; c2 = n2; c3 = n3;
    }
}

extern "C" void kernel_launch(void* const* d_in, const int* in_sizes, int n_in,
                              void* d_out, int out_size, void* d_ws, size_t ws_size,
                              hipStream_t stream) {
    const float* hs       = (const float*)d_in[0];
    const float* act      = (const float*)d_in[1];
    const float* w_norm   = (const float*)d_in[2];
    const float* W_router = (const float*)d_in[3];
    const float* W_pred   = (const float*)d_in[4];
    const float* W_corr   = (const float*)d_in[5];
    float* out = (float*)d_out;
    const long long T = (long long)in_sizes[0] / (4LL * H); // B*S

    const unsigned grid = (unsigned)((T + 3) / 4); // 4 tokens (waves) per block
    altup_deconvoy<<<dim3(grid), dim3(256), 0, stream>>>(
        hs, act, w_norm, W_router, W_pred, W_corr, out, T);
}

// Round 10
// 125.620 us; speedup vs baseline: 1.0112x; 1.0112x over previous
//
#include <hip/hip_runtime.h>

// Gemma3n AltUp fused, R10: R8's single-pass all-in-registers body (best,
// 117.5us) wrapped so each block processes 4 CONSECUTIVE tokens. Rationale:
// every structure pins at ~3.6 TB/s HBM; last untested lever is DRAM row
// locality — R8 retires 9 one-shot 8KB streams per block (~37k tiny streams
// chip-wide); here each block's 9 streams walk contiguous 32KB windows.
// (R5/R6 never tested this: their grid-stride token order jumped 16MB per
// iteration.) 2048 blocks x 128 thr = 8 blocks/CU resident, no tail.
// Shapes: hidden_states [4, T, H], activated [T, H], w_norm [H],
//         W_router [4, H], W_pred [16, 4], W_corr [4, 4], out [4, T, H]
// T = B*S = 8192, H = 2048, fp32.

constexpr int H = 2048;
constexpr int NC = 4;          // chunks per thread: H / (128 thr * 4 floats)
constexpr int TPB = 4;         // consecutive tokens per block
constexpr float EPS = 1e-6f;

typedef float f32x4 __attribute__((ext_vector_type(4)));

__global__ __launch_bounds__(128) void altup_tok4(
    const float* __restrict__ hs,       // [4, T, H]
    const float* __restrict__ act,      // [T, H]
    const float* __restrict__ w_norm,   // [H]
    const float* __restrict__ W_router, // [4, H]
    const float* __restrict__ W_pred,   // [16, 4]
    const float* __restrict__ W_corr,   // [4, 4]
    float* __restrict__ out,            // [4, T, H]
    long long T)
{
    const int tid = threadIdx.x;        // 0..127
    const long long plane = T * (long long)H;

    __shared__ float s_red[2][2][10];   // [tok parity][wave][partial]

    // hoisted token-invariant weight products
    f32x4 wnv[NC], wrv[4][NC];
#pragma unroll
    for (int c = 0; c < NC; ++c) {
        const int off = c * 512 + tid * 4;
        wnv[c] = *reinterpret_cast<const f32x4*>(w_norm + off);
#pragma unroll
        for (int i = 0; i < 4; ++i)
            wrv[i][c] = *reinterpret_cast<const f32x4*>(W_router + i * H + off);
    }

    for (int tok = 0; tok < TPB; ++tok) {
        const long long t = (long long)blockIdx.x * TPB + tok;
        if (t >= T) break;
        const long long row = t * (long long)H;

        // ---- single pass: plane-major bursty loads, all rows -> registers ----
        f32x4 x0[NC], xc[NC], x1[NC], x2[NC], x3[NC];
#pragma unroll
        for (int c = 0; c < NC; ++c)
            x0[c] = *reinterpret_cast<const f32x4*>(hs + row + c * 512 + tid * 4);
#pragma unroll
        for (int c = 0; c < NC; ++c)
            xc[c] = *reinterpret_cast<const f32x4*>(act + row + c * 512 + tid * 4);
#pragma unroll
        for (int c = 0; c < NC; ++c)
            x1[c] = *reinterpret_cast<const f32x4*>(hs + plane + row + c * 512 + tid * 4);
#pragma unroll
        for (int c = 0; c < NC; ++c)
            x2[c] = *reinterpret_cast<const f32x4*>(hs + 2 * plane + row + c * 512 + tid * 4);
#pragma unroll
        for (int c = 0; c < NC; ++c)
            x3[c] = *reinterpret_cast<const f32x4*>(hs + 3 * plane + row + c * 512 + tid * 4);

        // ---- partials ----
        float p[10];
#pragma unroll
        for (int i = 0; i < 10; ++i) p[i] = 0.f;
#pragma unroll
        for (int c = 0; c < NC; ++c) {
#pragma unroll
            for (int e = 0; e < 4; ++e) {
                p[0] += x0[c][e] * x0[c][e];
                p[5] += xc[c][e] * xc[c][e];
            }
#pragma unroll
            for (int i = 0; i < 4; ++i) {
                float da = 0.f, dc = 0.f;
#pragma unroll
                for (int e = 0; e < 4; ++e) {
                    const float wre = wnv[c][e] * wrv[i][c][e];
                    da += x0[c][e] * wre;
                    dc += xc[c][e] * wre;
                }
                p[1 + i] += da; p[6 + i] += dc;
            }
        }

        // ---- in-wave butterfly + single 2-wave LDS exchange (ping-pong) ----
#pragma unroll
        for (int m = 1; m < 64; m <<= 1) {
#pragma unroll
            for (int i = 0; i < 10; ++i) p[i] += __shfl_xor(p[i], m, 64);
        }
        const int buf = tok & 1;
        const int wv = tid >> 6;
        if ((tid & 63) == 0) {
#pragma unroll
            for (int i = 0; i < 10; ++i) s_red[buf][wv][i] = p[i];
        }
        __syncthreads();
        float tot[10];
#pragma unroll
        for (int i = 0; i < 10; ++i) tot[i] = s_red[buf][0][i] + s_red[buf][1][i];

        // ---- coefficient math (redundant per thread) ----
        const float ris = 1.0f / (float)H;
        const float inv_a = rsqrtf(tot[0] * ris + EPS) * ris;
        const float inv_c = rsqrtf(tot[5] * ris + EPS) * ris;
        float mods[4], modsc[4];
#pragma unroll
        for (int i = 0; i < 4; ++i) {
            mods[i]  = tanhf(tot[1 + i] * inv_a);
            modsc[i] = tanhf(tot[6 + i] * inv_c);
        }
        // coefT[k][j] = sum_m mods[m] * W_pred[(j*4+k)*4 + m]  (swapaxes folded)
        float coefT[4][4];
#pragma unroll
        for (int j = 0; j < 4; ++j)
#pragma unroll
            for (int k = 0; k < 4; ++k) {
                float s = 0.f;
#pragma unroll
                for (int m = 0; m < 4; ++m) s += mods[m] * W_pred[(j * 4 + k) * 4 + m];
                coefT[k][j] = s;
            }
        float ccoef[4];
#pragma unroll
        for (int j = 0; j < 4; ++j) {
            float s = 1.0f;
#pragma unroll
            for (int m = 0; m < 4; ++m) s += modsc[m] * W_corr[j * 4 + m];
            ccoef[j] = s;
        }

        // ---- plane-major stores (8KB burst per plane per token) ----
#pragma unroll
        for (int j = 0; j < 4; ++j) {
#pragma unroll
            for (int c = 0; c < NC; ++c) {
                f32x4 o;
#pragma unroll
                for (int e = 0; e < 4; ++e) {
                    const float xk[4] = { x0[c][e], x1[c][e], x2[c][e], x3[c][e] };
                    float pj = xk[j];
#pragma unroll
                    for (int k = 0; k < 4; ++k) pj += xk[k] * coefT[k][j];
                    float p0 = xk[0];
#pragma unroll
                    for (int k = 0; k < 4; ++k) p0 += xk[k] * coefT[k][0];
                    o[e] = pj + (xc[c][e] - p0) * ccoef[j];
                }
                *reinterpret_cast<f32x4*>(out + j * plane + row + c * 512 + tid * 4) = o;
            }
        }
    }
}

extern "C" void kernel_launch(void* const* d_in, const int* in_sizes, int n_in,
                              void* d_out, int out_size, void* d_ws, size_t ws_size,
                              hipStream_t stream) {
    const float* hs       = (const float*)d_in[0];
    const float* act      = (const float*)d_in[1];
    const float* w_norm   = (const float*)d_in[2];
    const float* W_router = (const float*)d_in[3];
    const float* W_pred   = (const float*)d_in[4];
    const float* W_corr   = (const float*)d_in[5];
    float* out = (float*)d_out;
    const long long T = (long long)in_sizes[0] / (4LL * H); // B*S

    const unsigned grid = (unsigned)((T + TPB - 1) / TPB);
    altup_tok4<<<dim3(grid), dim3(128), 0, stream>>>(
        hs, act, w_norm, W_router, W_pred, W_corr, out, T);
}

// Round 13
// 116.669 us; speedup vs baseline: 1.0887x; 1.0767x over previous
//
#include <hip/hip_runtime.h>

// Gemma3n AltUp fused — FINAL (revert to R8, the measured best at 117.5us).
// One token per 128-thread (2-wave) block, single pass, 4 chunks/thread.
// All 5 input rows live in registers; plane-major bursty loads and stores.
// Outputs recomputed per plane so no output regs held across the store loop.
//
// Optimization ledger (12 rounds):
//   R2  fused one-shot blocks           121.4us
//   R4  two-kernel split                144.4us (extra serial pass)
//   R5/R6 grid-stride pipeline          140-144us (fewer parallel streams)
//   R7  token-per-wave, no barriers     139.3us (+65MB re-read traffic)
//   R8  single-pass all-in-registers    117.5us  <== best
//   R9  fine-grained ld/st interleave   127.0us
//   R10 consecutive-token locality      125.6us
//   R11/R12 cache-bypass stores         broken (stale-cache read-back)
// Invariant: ~3.6 TB/s TCC-interface rate across ALL structures; only byte
// reduction moved the needle. Traffic is minimal (427MB: 262 write + 164
// fetch, fetch already < input size via L3 retention).
// Shapes: hidden_states [4, T, H], activated [T, H], w_norm [H],
//         W_router [4, H], W_pred [16, 4], W_corr [4, 4], out [4, T, H]
// T = B*S = 8192, H = 2048, fp32.

constexpr int H = 2048;
constexpr int NC = 4;          // chunks per thread: H / (128 thr * 4 floats)
constexpr float EPS = 1e-6f;

typedef float f32x4 __attribute__((ext_vector_type(4)));

__global__ __launch_bounds__(128) void altup_tok(
    const float* __restrict__ hs,       // [4, T, H]
    const float* __restrict__ act,      // [T, H]
    const float* __restrict__ w_norm,   // [H]
    const float* __restrict__ W_router, // [4, H]
    const float* __restrict__ W_pred,   // [16, 4]
    const float* __restrict__ W_corr,   // [4, 4]
    float* __restrict__ out,            // [4, T, H]
    long long T)
{
    const int tid = threadIdx.x;        // 0..127
    const long long t = blockIdx.x;
    const long long row = t * (long long)H;
    const long long plane = T * (long long)H;

    __shared__ float s_red[2][10];

    // ---- single pass: plane-major bursty loads, all rows -> registers ----
    f32x4 x0[NC], xc[NC], x1[NC], x2[NC], x3[NC];
#pragma unroll
    for (int c = 0; c < NC; ++c)
        x0[c] = *reinterpret_cast<const f32x4*>(hs + row + c * 512 + tid * 4);
#pragma unroll
    for (int c = 0; c < NC; ++c)
        xc[c] = *reinterpret_cast<const f32x4*>(act + row + c * 512 + tid * 4);
#pragma unroll
    for (int c = 0; c < NC; ++c)
        x1[c] = *reinterpret_cast<const f32x4*>(hs + plane + row + c * 512 + tid * 4);
#pragma unroll
    for (int c = 0; c < NC; ++c)
        x2[c] = *reinterpret_cast<const f32x4*>(hs + 2 * plane + row + c * 512 + tid * 4);
#pragma unroll
    for (int c = 0; c < NC; ++c)
        x3[c] = *reinterpret_cast<const f32x4*>(hs + 3 * plane + row + c * 512 + tid * 4);

    // ---- partials (weight loads broadcast-hot in L2/L3) ----
    float p[10];
#pragma unroll
    for (int i = 0; i < 10; ++i) p[i] = 0.f;
#pragma unroll
    for (int c = 0; c < NC; ++c) {
        const int off = c * 512 + tid * 4;
        const f32x4 wn = *reinterpret_cast<const f32x4*>(w_norm + off);
#pragma unroll
        for (int e = 0; e < 4; ++e) {
            p[0] += x0[c][e] * x0[c][e];
            p[5] += xc[c][e] * xc[c][e];
        }
#pragma unroll
        for (int i = 0; i < 4; ++i) {
            const f32x4 wr = *reinterpret_cast<const f32x4*>(W_router + i * H + off);
            float da = 0.f, dc = 0.f;
#pragma unroll
            for (int e = 0; e < 4; ++e) {
                const float wre = wn[e] * wr[e];
                da += x0[c][e] * wre;
                dc += xc[c][e] * wre;
            }
            p[1 + i] += da; p[6 + i] += dc;
        }
    }

    // ---- in-wave butterfly + single 2-wave LDS exchange ----
#pragma unroll
    for (int m = 1; m < 64; m <<= 1) {
#pragma unroll
        for (int i = 0; i < 10; ++i) p[i] += __shfl_xor(p[i], m, 64);
    }
    const int wv = tid >> 6;
    if ((tid & 63) == 0) {
#pragma unroll
        for (int i = 0; i < 10; ++i) s_red[wv][i] = p[i];
    }
    __syncthreads();
    float tot[10];
#pragma unroll
    for (int i = 0; i < 10; ++i) tot[i] = s_red[0][i] + s_red[1][i];

    // ---- coefficient math (redundant per thread) ----
    const float ris = 1.0f / (float)H;
    const float inv_a = rsqrtf(tot[0] * ris + EPS) * ris;
    const float inv_c = rsqrtf(tot[5] * ris + EPS) * ris;
    float mods[4], modsc[4];
#pragma unroll
    for (int i = 0; i < 4; ++i) {
        mods[i]  = tanhf(tot[1 + i] * inv_a);
        modsc[i] = tanhf(tot[6 + i] * inv_c);
    }
    // coefT[k][j] = sum_m mods[m] * W_pred[(j*4+k)*4 + m]  (swapaxes folded)
    float coefT[4][4];
#pragma unroll
    for (int j = 0; j < 4; ++j)
#pragma unroll
        for (int k = 0; k < 4; ++k) {
            float s = 0.f;
#pragma unroll
            for (int m = 0; m < 4; ++m) s += mods[m] * W_pred[(j * 4 + k) * 4 + m];
            coefT[k][j] = s;
        }
    float ccoef[4];
#pragma unroll
    for (int j = 0; j < 4; ++j) {
        float s = 1.0f;
#pragma unroll
        for (int m = 0; m < 4; ++m) s += modsc[m] * W_corr[j * 4 + m];
        ccoef[j] = s;
    }

    // ---- plane-major stores ----
    // out[j] = pred[j] + (xc - pred[0]) * ccoef[j]
#pragma unroll
    for (int j = 0; j < 4; ++j) {
#pragma unroll
        for (int c = 0; c < NC; ++c) {
            f32x4 o;
#pragma unroll
            for (int e = 0; e < 4; ++e) {
                const float xk[4] = { x0[c][e], x1[c][e], x2[c][e], x3[c][e] };
                float pj = xk[j];
#pragma unroll
                for (int k = 0; k < 4; ++k) pj += xk[k] * coefT[k][j];
                float p0 = xk[0];
#pragma unroll
                for (int k = 0; k < 4; ++k) p0 += xk[k] * coefT[k][0];
                o[e] = pj + (xc[c][e] - p0) * ccoef[j];
            }
            *reinterpret_cast<f32x4*>(out + j * plane + row + c * 512 + tid * 4) = o;
        }
    }
}

extern "C" void kernel_launch(void* const* d_in, const int* in_sizes, int n_in,
                              void* d_out, int out_size, void* d_ws, size_t ws_size,
                              hipStream_t stream) {
    const float* hs       = (const float*)d_in[0];
    const float* act      = (const float*)d_in[1];
    const float* w_norm   = (const float*)d_in[2];
    const float* W_router = (const float*)d_in[3];
    const float* W_pred   = (const float*)d_in[4];
    const float* W_corr   = (const float*)d_in[5];
    float* out = (float*)d_out;
    const long long T = (long long)in_sizes[0] / (4LL * H); // B*S

    altup_tok<<<dim3((unsigned)T), dim3(128), 0, stream>>>(
        hs, act, w_norm, W_router, W_pred, W_corr, out, T);
}